// Round 8
// baseline (712.666 us; speedup 1.0000x reference)
//
#include <hip/hip_runtime.h>
#include <hip/hip_bf16.h>
#include <stdint.h>

#define NN 50000
#define NE 800000
#define HH 128

typedef __bf16 bf16x8 __attribute__((ext_vector_type(8)));
typedef float  f32x4  __attribute__((ext_vector_type(4)));
typedef long   f8frag;   // 8 fp8 bytes = i64 MFMA operand

__device__ __forceinline__ unsigned short f2bf(float f) {
  union { float f; uint32_t u; } v; v.f = f;
  uint32_t r = v.u + 0x7FFFu + ((v.u >> 16) & 1u);
  return (unsigned short)(r >> 16);
}
__device__ __forceinline__ float b2f(unsigned short u) {
  union { float f; uint32_t u; } v; v.u = (uint32_t)u << 16; return v.f;
}
#if __has_builtin(__builtin_amdgcn_cvt_pk_bf16_f32)
typedef __bf16 bf16x2 __attribute__((ext_vector_type(2)));
__device__ __forceinline__ uint32_t pack2bf(float a, float b) {
  union { bf16x2 v; uint32_t u; } t;
  t.v = __builtin_amdgcn_cvt_pk_bf16_f32(a, b);
  return t.u;
}
#else
__device__ __forceinline__ uint32_t pack2bf(float a, float b) {
  return (uint32_t)f2bf(a) | ((uint32_t)f2bf(b) << 16);
}
#endif
__device__ __forceinline__ uint8_t f2fp8(float v) {
  return (uint8_t)(__builtin_amdgcn_cvt_pk_fp8_f32(v, 0.f, 0, false) & 0xff);
}
// fast silu/sigmoid
__device__ __forceinline__ float silu_f(float x) {
  return x * __builtin_amdgcn_rcpf(1.f + __expf(-x));
}
__device__ __forceinline__ float sigm_f(float x) {
  return __builtin_amdgcn_rcpf(1.f + __expf(-x));
}

// LDS tile blocks (bf16): [rows][32 k], 16B chunk c stored at c ^ ((row>>1)&3)
__device__ __forceinline__ bf16x8 frag_ld(const short* blk, int row, int q) {
  int c = q ^ ((row >> 1) & 3);
  return *(const bf16x8*)(blk + row * 32 + c * 8);
}
// bf16 global weight frag offset (swizzled prep layout, short-indexed)
__device__ __forceinline__ int wfrag_off(int row, int q) {
  return row * 32 + ((q ^ ((row >> 1) & 3)) * 8);
}
// build bf16x8 frag from 8 consecutive f32 (16B-aligned), with scale folded
__device__ __forceinline__ bf16x8 fragf32(const float* src, float sc) {
  float4 lo = *(const float4*)src;
  float4 hi = *(const float4*)(src + 4);
  union { uint32_t u[4]; bf16x8 v; } t;
  t.u[0] = pack2bf(lo.x * sc, lo.y * sc);
  t.u[1] = pack2bf(lo.z * sc, lo.w * sc);
  t.u[2] = pack2bf(hi.x * sc, hi.y * sc);
  t.u[3] = pack2bf(hi.z * sc, hi.w * sc);
  return t.v;
}

// ---------------- weight prep body ----------------
__device__ void prep_weights_body(int idx, const float* We1, const float* We2,
                                  const float* Wn1, const float* Wn2,
                                  const float* cW1, const float* cW2,
                                  uint8_t* W1f8, short* W2sw, short* Wn1sw,
                                  short* Wn2sw, short* W1csw) {
  if (idx < 110592) {                      // fp8 W1 (ks=265)
    int l = idx / 36864, rem = idx % 36864;
    const float* s = (l == 0) ? We1 : (l == 1) ? We1 + 33920 : cW1;
    int kkb = rem >> 12, r2 = rem & 4095;
    int n = r2 >> 5, kw = r2 & 31;
    int k = kkb * 32 + kw;
    float v = (k < 265) ? s[k * 128 + n] : 0.f;
    W1f8[idx] = f2fp8(v);
    return;
  }
  idx -= 110592;
  if (idx < 49152) {                       // bf16 W2, 3 sets, ks=128
    int l = idx >> 14, rem = idx & 16383;
    const float* s = (l == 0) ? We2 : (l == 1) ? We2 + 16384 : cW2;
    int kkb = rem >> 12, r2 = rem & 4095, n = r2 >> 5, kw = r2 & 31;
    int cp = kw >> 3, j = kw & 7, c = cp ^ ((n >> 1) & 3);
    int k = kkb * 32 + c * 8 + j;
    W2sw[(l << 14) + (rem)] = (short)f2bf(s[k * 128 + n]);
    return;
  }
  idx -= 49152;
  if (idx < 65536) {                       // bf16 Wn1, 2 sets, ks=256
    int l = idx >> 15, rem = idx & 32767;
    const float* s = Wn1 + l * 32768;
    int kkb = rem >> 12, r2 = rem & 4095, n = r2 >> 5, kw = r2 & 31;
    int cp = kw >> 3, j = kw & 7, c = cp ^ ((n >> 1) & 3);
    int k = kkb * 32 + c * 8 + j;
    Wn1sw[(l << 15) + rem] = (short)f2bf(s[k * 128 + n]);
    return;
  }
  idx -= 65536;
  if (idx < 32768) {                       // bf16 Wn2, 2 sets, ks=128
    int l = idx >> 14, rem = idx & 16383;
    const float* s = Wn2 + l * 16384;
    int kkb = rem >> 12, r2 = rem & 4095, n = r2 >> 5, kw = r2 & 31;
    int cp = kw >> 3, j = kw & 7, c = cp ^ ((n >> 1) & 3);
    int k = kkb * 32 + c * 8 + j;
    Wn2sw[(l << 14) + rem] = (short)f2bf(s[k * 128 + n]);
    return;
  }
  idx -= 32768;
  if (idx < 98304) {                       // bf16 W1cat, 3 sets, [4kk][256n][32k]
    int l = idx / 32768, rem = idx % 32768;
    const float* s = (l == 0) ? We1 : (l == 1) ? We1 + 33920 : cW1;
    int kkb = rem >> 13, r2 = rem & 8191, n = r2 >> 5, kw = r2 & 31;
    int cp = kw >> 3, j = kw & 7, c = cp ^ ((n >> 1) & 3);
    int k = kkb * 32 + c * 8 + j;          // 0..127
    float v = (n < 128) ? s[k * 128 + n] : s[(128 + k) * 128 + (n - 128)];
    W1csw[l * 32768 + rem] = (short)f2bf(v);
  }
}

// fused: weight prep (blocks 0..1391) + edge histogram (blocks 1392..)
__global__ void k_setup1(const float* We1, const float* We2, const float* Wn1,
                         const float* Wn2, const float* cW1, const float* cW2,
                         uint8_t* W1f8, short* W2sw, short* Wn1sw, short* Wn2sw,
                         short* W1csw, const int* __restrict__ ei,
                         int* __restrict__ cnt) {
  if (blockIdx.x < 1392) {
    prep_weights_body(blockIdx.x * 256 + threadIdx.x, We1, We2, Wn1, Wn2, cW1, cW2,
                      W1f8, W2sw, Wn1sw, Wn2sw, W1csw);
  } else {
    int e = (blockIdx.x - 1392) * 256 + threadIdx.x;
    if (e < NE) atomicAdd(&cnt[ei[e]], 1);
  }
}

// ---------------- small prep / epilogue kernels ----------------
// forward-perm: per sorted slot p, gather original edge e = sortedIdx[p];
// all writes coalesced. Also zeroes pagg (folds a memset dispatch).
__global__ void k_edge_pre(const float* __restrict__ pos, const float* __restrict__ eattr,
                           const int* __restrict__ ei, const int* __restrict__ sortedIdx,
                           int* __restrict__ rowS, int* __restrict__ colS,
                           uint8_t* __restrict__ eaF8, float* __restrict__ ndS,
                           float* __restrict__ pagg) {
  int p = blockIdx.x * 256 + threadIdx.x;
  if (p < NN * 3) pagg[p] = 0.f;
  if (p >= NE) return;
  int e = sortedIdx[p];
  int r = ei[e], c = ei[NE + e];
  float dx = pos[r * 3 + 0] - pos[c * 3 + 0];
  float dy = pos[r * 3 + 1] - pos[c * 3 + 1];
  float dz = pos[r * 3 + 2] - pos[c * 3 + 2];
  float d2 = dx * dx + dy * dy + dz * dz;
  float invd = __builtin_amdgcn_rcpf(sqrtf(d2) + 1.f);   // NC = 1.0
  rowS[p] = r;
  colS[p] = c;
  ndS[p * 3 + 0] = dx * invd;
  ndS[p * 3 + 1] = dy * invd;
  ndS[p * 3 + 2] = dz * invd;
  const float* ea = eattr + (size_t)e * 8;
  uint32_t w0 = __builtin_amdgcn_cvt_pk_fp8_f32(d2, ea[0], 0, false);
  w0 = __builtin_amdgcn_cvt_pk_fp8_f32(ea[1], ea[2], w0, true);
  uint32_t w1 = __builtin_amdgcn_cvt_pk_fp8_f32(ea[3], ea[4], 0, false);
  w1 = __builtin_amdgcn_cvt_pk_fp8_f32(ea[5], ea[6], w1, true);
  uint32_t w2 = __builtin_amdgcn_cvt_pk_fp8_f32(ea[7], 0.f, 0, false);
  uint4 v = {w0, w1, w2, 0u};
  *(uint4*)(eaF8 + (size_t)p * 16) = v;
}
__global__ void k_pos_final(const float* __restrict__ pos, const float* __restrict__ mask,
                            const float* __restrict__ pagg, float* __restrict__ out) {
  int i = blockIdx.x * 256 + threadIdx.x;
  if (i < NN * 3) out[i] = pos[i] + pagg[i] * 0.01f * mask[i / 3];
}

// ---------------- CSR sort: scans ----------------
__global__ void k_scan_block(const int* __restrict__ cnt, int* __restrict__ offs,
                             int* __restrict__ bsum) {
  __shared__ int s[256];
  int i = blockIdx.x * 256 + threadIdx.x;
  int v = (i < NN) ? cnt[i] : 0;
  s[threadIdx.x] = v;
  __syncthreads();
#pragma unroll
  for (int d = 1; d < 256; d <<= 1) {
    int t = (threadIdx.x >= d) ? s[threadIdx.x - d] : 0;
    __syncthreads();
    s[threadIdx.x] += t;
    __syncthreads();
  }
  if (i < NN) offs[i] = s[threadIdx.x] - v;
  if (threadIdx.x == 255) bsum[blockIdx.x] = s[255];
}
__global__ void k_scan_top(int* __restrict__ bsum) {
  __shared__ int s[256];
  int v = (threadIdx.x < 196) ? bsum[threadIdx.x] : 0;
  s[threadIdx.x] = v;
  __syncthreads();
#pragma unroll
  for (int d = 1; d < 256; d <<= 1) {
    int t = (threadIdx.x >= d) ? s[threadIdx.x - d] : 0;
    __syncthreads();
    s[threadIdx.x] += t;
    __syncthreads();
  }
  if (threadIdx.x < 196) bsum[threadIdx.x] = s[threadIdx.x] - v;
}

// ---------------- per-node H1 body (layer 0, reads x f32; zeroes agg) ----------------
__device__ void h1_body(int tile, int tid, const float* __restrict__ x,
                        const short* __restrict__ W1c, const float* __restrict__ b1,
                        short* __restrict__ H1RC, float* __restrict__ aggZ) {
  const int lane = tid & 63, w = tid >> 6;
  const int ln = lane & 15, q = lane >> 4;
  {
    float4* a4 = (float4*)aggZ;
    const float4 z4 = {0.f, 0.f, 0.f, 0.f};
#pragma unroll
    for (int k = 0; k < 8; ++k) {
      int i4 = tile * 2048 + k * 256 + tid;
      if (i4 < NN * 32) a4[i4] = z4;
    }
  }
  size_t nbase[4];
  int wofs[4];
#pragma unroll
  for (int i = 0; i < 4; ++i) {
    int node = tile * 64 + i * 16 + ln;
    nbase[i] = (size_t)(node < NN ? node : (NN - 1)) * 128;
    int row = w * 64 + i * 16 + ln;
    wofs[i] = row * 32 + ((q ^ ((row >> 1) & 3)) * 8);
  }
  f32x4 acc[4][4];
  const f32x4 zero4 = {0.f, 0.f, 0.f, 0.f};
#pragma unroll
  for (int mi = 0; mi < 4; ++mi)
#pragma unroll
    for (int ni = 0; ni < 4; ++ni) acc[mi][ni] = zero4;
#pragma unroll
  for (int kk = 0; kk < 4; ++kk) {
    bf16x8 af[4], bfr[4];
#pragma unroll
    for (int i = 0; i < 4; ++i) af[i] = fragf32(x + nbase[i] + kk * 32 + q * 8, 1.f);
#pragma unroll
    for (int i = 0; i < 4; ++i) bfr[i] = *(const bf16x8*)(W1c + kk * 8192 + wofs[i]);
#pragma unroll
    for (int mi = 0; mi < 4; ++mi)
#pragma unroll
      for (int ni = 0; ni < 4; ++ni)
        acc[mi][ni] = __builtin_amdgcn_mfma_f32_16x16x32_bf16(af[mi], bfr[ni], acc[mi][ni], 0, 0, 0);
  }
  float b1v[4];
#pragma unroll
  for (int ni = 0; ni < 4; ++ni) {
    int ch = w * 64 + ni * 16 + ln;
    b1v[ni] = (ch < 128) ? b1[ch] : 0.f;
  }
#pragma unroll
  for (int mi = 0; mi < 4; ++mi)
#pragma unroll
    for (int r = 0; r < 4; ++r) {
      int node = tile * 64 + mi * 16 + q * 4 + r;
      if (node < NN) {
        ushort4 pk;
        pk.x = f2bf(acc[mi][0][r] + b1v[0]);
        pk.y = f2bf(acc[mi][1][r] + b1v[1]);
        pk.z = f2bf(acc[mi][2][r] + b1v[2]);
        pk.w = f2bf(acc[mi][3][r] + b1v[3]);
        *(ushort4*)(H1RC + (size_t)node * 256 + w * 64 + ln * 4) = pk;
      }
    }
}

// fused: layer-0 H1 (blocks 0..781) + sort scatter (blocks 782..)
// scatter folds the scan_add: slot = local prefix atomic + block base
__global__ __launch_bounds__(256) void k_setup2(
    const float* __restrict__ x, const short* __restrict__ W1c,
    const float* __restrict__ b1, short* __restrict__ H1RC, float* __restrict__ aggZ,
    const int* __restrict__ ei, int* __restrict__ offs, const int* __restrict__ bsum,
    int* __restrict__ sortedIdx) {
  if (blockIdx.x < 782) {
    h1_body(blockIdx.x, threadIdx.x, x, W1c, b1, H1RC, aggZ);
  } else {
    int e = (blockIdx.x - 782) * 256 + threadIdx.x;
    if (e < NE) {
      int r = ei[e];
      sortedIdx[atomicAdd(&offs[r], 1) + bsum[r >> 8]] = e;
    }
  }
}

// ---------------- fused edge/coord MLP (edges presorted by row) ----------------
// h1 = silu(H1RC[row].lo + H1RC[col].hi + ea@W1ea). Attention rides in the
// segment-sum S matrix. XCD-bijective tile swizzle. SINGLE accumulator array
// reused by GEMM1 and GEMM2 (keeps peak regs ~80 -> 5 blocks/CU).
// Interior runs (rows wholly inside this tile) use plain stores, not atomics.
template <int COORD>
__global__ __launch_bounds__(256, 5) void k_edge_gemm(
    const short* __restrict__ H1RC, const uint8_t* __restrict__ eaF8,
    const int* __restrict__ rowS, const int* __restrict__ colS,
    const uint8_t* __restrict__ W1f8, const short* __restrict__ W2l,
    const float* __restrict__ b2,
    const float* __restrict__ wred, const float* __restrict__ batt,
    const float* __restrict__ ndS, float* outAcc) {
  __shared__ __align__(16) short A2s[8192];  // h1^T 4x[64e][32c]; then M 2x[128c][32e]
  __shared__ float redp[64][2];
  __shared__ __align__(16) unsigned short attb[64];
  __shared__ int srow[64];
  __shared__ __align__(8) unsigned char srunS[64];
  __shared__ int runrowS[64];
  __shared__ int cntS[1];

  const int tid = threadIdx.x;
  const int lane = tid & 63;
  const int w = tid >> 6;
  const int ln = lane & 15, q = lane >> 4;
  const int wm = w >> 1, wn = w & 1;

  // XCD-bijective swizzle (8 XCDs)
  const int nwg = gridDim.x;
  const int qq = nwg >> 3, rr = nwg & 7;
  const int xcd = blockIdx.x & 7, bidx = blockIdx.x >> 3;
  const int tile = (xcd < rr ? xcd * (qq + 1) : rr * (qq + 1) + (xcd - rr) * qq) + bidx;
  const int ebase = tile * 64;

  // ---- wave0: segmented-run scan over sorted rows (published by epilogue1 barrier)
  bool is_start = false;
  if (w == 0) {
    int myrow = rowS[ebase + tid];
    srow[tid] = myrow;
    int prevrow = (tid > 0) ? rowS[ebase + tid - 1] : (myrow ^ 1);
    is_start = (tid == 0) || (myrow != prevrow);
    unsigned long long bmask = __ballot(is_start);
    if (tid == 0) cntS[0] = __popcll(bmask);
    int run = __popcll(bmask & ((1ull << lane) - 1ull)) + (is_start ? 1 : 0) - 1;
    srunS[tid] = (unsigned char)run;
    if (is_start) runrowS[run] = myrow;
  }

  // per-lane sources (uint32 offsets -> saddr-form loads)
  const int e0 = wm * 32 + ln, e1 = e0 + 16;
  const uint32_t cbp = (uint32_t)(wn * 64 + q * 16);
  const uint32_t hr0 = (uint32_t)rowS[ebase + e0] * 256u + cbp;
  const uint32_t hr1 = (uint32_t)rowS[ebase + e1] * 256u + cbp;
  const uint32_t hc0 = (uint32_t)colS[ebase + e0] * 256u + 128u + cbp;
  const uint32_t hc1 = (uint32_t)colS[ebase + e1] * 256u + 128u + cbp;
  const uint32_t ea0 = (uint32_t)(ebase + e0) * 16u + (uint32_t)((q & 1) * 8);
  const uint32_t ea1 = (uint32_t)(ebase + e1) * 16u + (uint32_t)((q & 1) * 8);
  int wofs8[4], wofs[4];
#pragma unroll
  for (int i = 0; i < 4; ++i) {
    wofs8[i] = (wn * 64 + i * 16 + ln) * 32 + q * 8;
    wofs[i] = wfrag_off(wn * 64 + i * 16 + ln, q);
  }

  // H1 gathers: 16B each
  union U8 { uint4 v; unsigned short s[8]; };
  U8 xr[2][2], xc[2][2];
  xr[0][0].v = *(const uint4*)(H1RC + hr0);
  xr[0][1].v = *(const uint4*)(H1RC + hr0 + 8);
  xr[1][0].v = *(const uint4*)(H1RC + hr1);
  xr[1][1].v = *(const uint4*)(H1RC + hr1 + 8);
  xc[0][0].v = *(const uint4*)(H1RC + hc0);
  xc[0][1].v = *(const uint4*)(H1RC + hc0 + 8);
  xc[1][0].v = *(const uint4*)(H1RC + hc1);
  xc[1][1].v = *(const uint4*)(H1RC + hc1 + 8);

  f32x4 acc[4][2];                           // reused: GEMM1 then GEMM2
  const f32x4 zero4 = {0.f, 0.f, 0.f, 0.f};
#pragma unroll
  for (int ni = 0; ni < 4; ++ni)
#pragma unroll
    for (int mi = 0; mi < 2; ++mi) acc[ni][mi] = zero4;

  // -------- ea-only fp8 MFMA step --------
  {
    const uint8_t* W1ea = W1f8 + 8 * 4096;
    f8frag wf[4], hf[2];
#pragma unroll
    for (int i = 0; i < 4; ++i) wf[i] = *(const f8frag*)(W1ea + wofs8[i]);
    hf[0] = (q < 2) ? *(const f8frag*)(eaF8 + ea0) : 0L;
    hf[1] = (q < 2) ? *(const f8frag*)(eaF8 + ea1) : 0L;
#pragma unroll
    for (int ni = 0; ni < 4; ++ni)
#pragma unroll
      for (int mi = 0; mi < 2; ++mi)
        acc[ni][mi] = __builtin_amdgcn_mfma_f32_16x16x32_fp8_fp8(wf[ni], hf[mi], acc[ni][mi], 0, 0, 0);
  }

  // -------- epilogue1: silu(ea + H1R[row] + H1C[col]) -> A2s bf16 [edge][chan] --------
#pragma unroll
  for (int ni = 0; ni < 4; ++ni) {
    int cb = wn * 64 + ni * 16 + q * 4;
    int kkb = cb >> 5, cc = (cb >> 3) & 3, j0 = cb & 7;
#pragma unroll
    for (int mi = 0; mi < 2; ++mi) {
      int edge = wm * 32 + mi * 16 + ln;
      int addr = kkb * 2048 + edge * 32 + ((cc ^ ((edge >> 1) & 3)) * 8) + j0;
      float h0 = silu_f(acc[ni][mi][0] + b2f(xr[mi][0].s[ni]) + b2f(xc[mi][0].s[ni]));
      float h1 = silu_f(acc[ni][mi][1] + b2f(xr[mi][0].s[4 + ni]) + b2f(xc[mi][0].s[4 + ni]));
      float h2 = silu_f(acc[ni][mi][2] + b2f(xr[mi][1].s[ni]) + b2f(xc[mi][1].s[ni]));
      float h3 = silu_f(acc[ni][mi][3] + b2f(xr[mi][1].s[4 + ni]) + b2f(xc[mi][1].s[4 + ni]));
      uint2 pk;
      pk.x = pack2bf(h0, h1);
      pk.y = pack2bf(h2, h3);
      *(uint2*)(A2s + addr) = pk;
    }
  }
  __syncthreads();

  // -------- GEMM2 (bf16) into the SAME acc registers --------
#pragma unroll
  for (int ni = 0; ni < 4; ++ni)
#pragma unroll
    for (int mi = 0; mi < 2; ++mi) acc[ni][mi] = zero4;
#pragma unroll
  for (int kk = 0; kk < 4; ++kk) {
    bf16x8 wf[4], hf[2];
#pragma unroll
    for (int i = 0; i < 4; ++i) wf[i] = *(const bf16x8*)(W2l + kk * 4096 + wofs[i]);
#pragma unroll
    for (int i = 0; i < 2; ++i) hf[i] = frag_ld(A2s + kk * 2048, wm * 32 + i * 16 + ln, q);
#pragma unroll
    for (int ni = 0; ni < 4; ++ni)
#pragma unroll
      for (int mi = 0; mi < 2; ++mi)
        acc[ni][mi] = __builtin_amdgcn_mfma_f32_16x16x32_bf16(wf[ni], hf[mi], acc[ni][mi], 0, 0, 0);
  }

  // -------- epilogue2: silu + attention/phi dot --------
  float4 b2v[4], wv[4];
#pragma unroll
  for (int ni = 0; ni < 4; ++ni) {
    b2v[ni] = *(const float4*)(b2 + wn * 64 + ni * 16 + q * 4);
    wv[ni]  = *(const float4*)(wred + wn * 64 + ni * 16 + q * 4);
  }
  float p[2] = {0.f, 0.f};
#pragma unroll
  for (int ni = 0; ni < 4; ++ni)
#pragma unroll
    for (int mi = 0; mi < 2; ++mi)
#pragma unroll
      for (int r = 0; r < 4; ++r) {
        float v = silu_f(acc[ni][mi][r] + ((const float*)&b2v[ni])[r]);
        acc[ni][mi][r] = v;
        p[mi] += v * ((const float*)&wv[ni])[r];
      }
#pragma unroll
  for (int mi = 0; mi < 2; ++mi) {
    p[mi] += __shfl_xor(p[mi], 16, 64);
    p[mi] += __shfl_xor(p[mi], 32, 64);
  }
  if (lane < 16) {
#pragma unroll
    for (int mi = 0; mi < 2; ++mi) redp[wm * 32 + mi * 16 + ln][wn] = p[mi];
  }
  __syncthreads();   // redp ready; all waves done with A2s

  if (COORD == 0) {
    if (tid < 64) attb[tid] = f2bf(sigm_f(redp[tid][0] + redp[tid][1] + batt[0]));
#pragma unroll
    for (int ni = 0; ni < 4; ++ni)
#pragma unroll
      for (int mi = 0; mi < 2; ++mi) {
        int eb = mi * 16 + ln;
        int cE = (eb >> 3) & 3, jE = eb & 7;
#pragma unroll
        for (int r = 0; r < 4; ++r) {
          int chan2 = wn * 64 + ni * 16 + q * 4 + r;
          int addr = wm * 4096 + chan2 * 32 + ((cE ^ ((chan2 >> 1) & 3)) * 8) + jE;
          union { float f; uint32_t u; } vv;
          vv.f = acc[ni][mi][r];
          A2s[addr] = (short)((vv.u + 0x8000u) >> 16);
        }
      }
    __syncthreads();   // attb + M ready
    // segment-sum via MFMA: agg[run][chan] = S[run][edge] @ M[edge][chan]
    const int nruns = cntS[0];
    bf16x8 bfrg[2][2];
#pragma unroll
    for (int kk = 0; kk < 2; ++kk)
#pragma unroll
      for (int ni = 0; ni < 2; ++ni)
        bfrg[kk][ni] = frag_ld(A2s + kk * 4096, w * 32 + ni * 16 + ln, q);
    const int npass = (nruns + 15) >> 4;
    for (int pp = 0; pp < npass; ++pp) {
      const unsigned int base = pp * 16;
      f32x4 a3c[2] = {zero4, zero4};
#pragma unroll
      for (int kk = 0; kk < 2; ++kk) {
        uint2 sb = *(const uint2*)(srunS + kk * 32 + q * 8);
        U8 ab;
        ab.v = *(const uint4*)(attb + kk * 32 + q * 8);
        union { short s[8]; bf16x8 v; } af;
#pragma unroll
        for (int j = 0; j < 4; ++j)
          af.s[j] = (((sb.x >> (8 * j)) & 255u) == base + (unsigned)ln) ? (short)ab.s[j] : (short)0;
#pragma unroll
        for (int j = 0; j < 4; ++j)
          af.s[4 + j] = (((sb.y >> (8 * j)) & 255u) == base + (unsigned)ln) ? (short)ab.s[4 + j] : (short)0;
        a3c[0] = __builtin_amdgcn_mfma_f32_16x16x32_bf16(af.v, bfrg[kk][0], a3c[0], 0, 0, 0);
        a3c[1] = __builtin_amdgcn_mfma_f32_16x16x32_bf16(af.v, bfrg[kk][1], a3c[1], 0, 0, 0);
      }
#pragma unroll
      for (int ni = 0; ni < 2; ++ni)
#pragma unroll
        for (int r = 0; r < 4; ++r) {
          int run = (int)base + q * 4 + r;
          if (run < nruns) {
            int rw = runrowS[run];
            float* dst = &outAcc[(size_t)rw * 128 + (w * 32 + ni * 16 + ln)];
            // interior run: row wholly inside this tile -> exclusive, plain store
            if (run > 0 && run < nruns - 1) *dst = a3c[ni][r];
            else atomicAdd(dst, a3c[ni][r]);
          }
        }
    }
  } else {
    float* ndl = (float*)A2s;   // reuse: [64][3]
    if (tid < 64) {
      float phi = redp[tid][0] + redp[tid][1];
      ndl[tid * 3 + 0] = ndS[(size_t)(ebase + tid) * 3 + 0] * phi;
      ndl[tid * 3 + 1] = ndS[(size_t)(ebase + tid) * 3 + 1] * phi;
      ndl[tid * 3 + 2] = ndS[(size_t)(ebase + tid) * 3 + 2] * phi;
    }
    __syncthreads();
    if (is_start) {   // run-start walkers (wave0 only)
      int myrow = srow[tid];
      float s0 = 0.f, s1 = 0.f, s2 = 0.f;
      int j = tid;
      for (; j < 64 && srow[j] == myrow; ++j) {
        s0 += ndl[j * 3 + 0];
        s1 += ndl[j * 3 + 1];
        s2 += ndl[j * 3 + 2];
      }
      bool excl = (tid > 0) && (j < 64);   // run starts and ends inside tile
      if (excl) {
        outAcc[myrow * 3 + 0] = s0;
        outAcc[myrow * 3 + 1] = s1;
        outAcc[myrow * 3 + 2] = s2;
      } else {
        atomicAdd(&outAcc[myrow * 3 + 0], s0);
        atomicAdd(&outAcc[myrow * 3 + 1], s1);
        atomicAdd(&outAcc[myrow * 3 + 2], s2);
      }
    }
  }
}

// ---------------- node MLP GEMM + fused next-layer H1 (64-node tiles, bf16) ----------
__global__ __launch_bounds__(256) void k_node_gemm(
    const float* __restrict__ agg,
    const short* __restrict__ Wn1l, const short* __restrict__ Wn2l,
    const float* __restrict__ b1, const float* __restrict__ b2,
    const float* __restrict__ xres, float* __restrict__ xout,
    const short* __restrict__ W1cN, const float* __restrict__ b1N,
    short* __restrict__ H1RC, float* __restrict__ aggZ) {
  __shared__ short A2s[4 * 2048];

  const int tid = threadIdx.x;
  const int lane = tid & 63;
  const int w = tid >> 6;
  const int ln = lane & 15, q = lane >> 4;
  const int wm = w >> 1, wn = w & 1;
  const int tile = blockIdx.x;

  size_t nbase[2];
  int wofs[4];
#pragma unroll
  for (int i = 0; i < 2; ++i) {
    int node = tile * 64 + wm * 32 + i * 16 + ln;
    nbase[i] = (size_t)(node < NN ? node : (NN - 1)) * 128;
  }
#pragma unroll
  for (int i = 0; i < 4; ++i) wofs[i] = wfrag_off(wn * 64 + i * 16 + ln, q);

  f32x4 acc[2][4];
  const f32x4 zero4 = {0.f, 0.f, 0.f, 0.f};
#pragma unroll
  for (int mi = 0; mi < 2; ++mi)
#pragma unroll
    for (int ni = 0; ni < 4; ++ni) acc[mi][ni] = zero4;

#pragma unroll
  for (int kk = 0; kk < 8; ++kk) {
    bf16x8 af[2], bfr[4];
#pragma unroll
    for (int i = 0; i < 2; ++i) {
      if (kk < 4) af[i] = fragf32(xres + nbase[i] + kk * 32 + q * 8, 1.f);
      else        af[i] = fragf32(agg + nbase[i] + (kk - 4) * 32 + q * 8, 0.01f);
    }
#pragma unroll
    for (int i = 0; i < 4; ++i) bfr[i] = *(const bf16x8*)(Wn1l + kk * 4096 + wofs[i]);
#pragma unroll
    for (int mi = 0; mi < 2; ++mi)
#pragma unroll
      for (int ni = 0; ni < 4; ++ni)
        acc[mi][ni] = __builtin_amdgcn_mfma_f32_16x16x32_bf16(af[mi], bfr[ni], acc[mi][ni], 0, 0, 0);
  }

  if (aggZ) {
    float4* a4 = (float4*)aggZ;
    const float4 z4 = {0.f, 0.f, 0.f, 0.f};
#pragma unroll
    for (int k = 0; k < 8; ++k) {
      int i4 = tile * 2048 + k * 256 + tid;
      if (i4 < NN * 32) a4[i4] = z4;
    }
  }

  float b1v[4];
#pragma unroll
  for (int ni = 0; ni < 4; ++ni) b1v[ni] = b1[wn * 64 + ni * 16 + ln];
#pragma unroll
  for (int mi = 0; mi < 2; ++mi)
#pragma unroll
    for (int ni = 0; ni < 4; ++ni) {
      int chan = wn * 64 + ni * 16 + ln;
      int kkb = chan >> 5, c = (chan >> 3) & 3, jj = chan & 7;
#pragma unroll
      for (int r = 0; r < 4; ++r) {
        int m = wm * 32 + mi * 16 + q * 4 + r;
        float v = silu_f(acc[mi][ni][r] + b1v[ni]);
        A2s[kkb * 2048 + m * 32 + ((c ^ ((m >> 1) & 3)) * 8) + jj] = (short)f2bf(v);
      }
    }
  __syncthreads();

  f32x4 acc2[2][4];
#pragma unroll
  for (int mi = 0; mi < 2; ++mi)
#pragma unroll
    for (int ni = 0; ni < 4; ++ni) acc2[mi][ni] = zero4;
#pragma unroll
  for (int kk = 0; kk < 4; ++kk) {
    bf16x8 af[2], bfr[4];
#pragma unroll
    for (int i = 0; i < 2; ++i) af[i] = frag_ld(A2s + kk * 2048, wm * 32 + i * 16 + ln, q);
#pragma unroll
    for (int i = 0; i < 4; ++i) bfr[i] = *(const bf16x8*)(Wn2l + kk * 4096 + wofs[i]);
#pragma unroll
    for (int mi = 0; mi < 2; ++mi)
#pragma unroll
      for (int ni = 0; ni < 4; ++ni)
        acc2[mi][ni] = __builtin_amdgcn_mfma_f32_16x16x32_bf16(af[mi], bfr[ni], acc2[mi][ni], 0, 0, 0);
  }

  float b2v[4];
#pragma unroll
  for (int ni = 0; ni < 4; ++ni) b2v[ni] = b2[wn * 64 + ni * 16 + ln];
#pragma unroll
  for (int mi = 0; mi < 2; ++mi)
#pragma unroll
    for (int r = 0; r < 4; ++r) {
      int m = wm * 32 + mi * 16 + q * 4 + r;
      int node = tile * 64 + m;
      if (node < NN) {
#pragma unroll
        for (int ni = 0; ni < 4; ++ni) {
          int chan = wn * 64 + ni * 16 + ln;
          float v = acc2[mi][ni][r] + b2v[ni] + xres[(size_t)node * 128 + chan];
          acc2[mi][ni][r] = v;
          xout[(size_t)node * 128 + chan] = v;
        }
      }
    }

  // ---- fused H1 for the next stage ----
  __syncthreads();
#pragma unroll
  for (int mi = 0; mi < 2; ++mi)
#pragma unroll
    for (int ni = 0; ni < 4; ++ni) {
      int chan = wn * 64 + ni * 16 + ln;
      int kkb = chan >> 5, c = (chan >> 3) & 3, jj = chan & 7;
#pragma unroll
      for (int r = 0; r < 4; ++r) {
        int m = wm * 32 + mi * 16 + q * 4 + r;
        A2s[kkb * 2048 + m * 32 + ((c ^ ((m >> 1) & 3)) * 8) + jj] = (short)f2bf(acc2[mi][ni][r]);
      }
    }
  __syncthreads();

  int wofsH[4];
#pragma unroll
  for (int i = 0; i < 4; ++i) {
    int row = w * 64 + i * 16 + ln;
    wofsH[i] = row * 32 + ((q ^ ((row >> 1) & 3)) * 8);
  }
  f32x4 acc3[4][4];
#pragma unroll
  for (int mi = 0; mi < 4; ++mi)
#pragma unroll
    for (int ni = 0; ni < 4; ++ni) acc3[mi][ni] = zero4;
#pragma unroll
  for (int kk = 0; kk < 4; ++kk) {
    bf16x8 af[4], bfr[4];
#pragma unroll
    for (int i = 0; i < 4; ++i) af[i] = frag_ld(A2s + kk * 2048, i * 16 + ln, q);
#pragma unroll
    for (int i = 0; i < 4; ++i) bfr[i] = *(const bf16x8*)(W1cN + kk * 8192 + wofsH[i]);
#pragma unroll
    for (int mi = 0; mi < 4; ++mi)
#pragma unroll
      for (int ni = 0; ni < 4; ++ni)
        acc3[mi][ni] = __builtin_amdgcn_mfma_f32_16x16x32_bf16(af[mi], bfr[ni], acc3[mi][ni], 0, 0, 0);
  }
  float b1v2[4];
#pragma unroll
  for (int ni = 0; ni < 4; ++ni) {
    int ch = w * 64 + ni * 16 + ln;
    b1v2[ni] = (ch < 128) ? b1N[ch] : 0.f;
  }
#pragma unroll
  for (int mi = 0; mi < 4; ++mi)
#pragma unroll
    for (int r = 0; r < 4; ++r) {
      int node = tile * 64 + mi * 16 + q * 4 + r;
      if (node < NN) {
        ushort4 pk;
        pk.x = f2bf(acc3[mi][0][r] + b1v2[0]);
        pk.y = f2bf(acc3[mi][1][r] + b1v2[1]);
        pk.z = f2bf(acc3[mi][2][r] + b1v2[2]);
        pk.w = f2bf(acc3[mi][3][r] + b1v2[3]);
        *(ushort4*)(H1RC + (size_t)node * 256 + w * 64 + ln * 4) = pk;
      }
    }
}

extern "C" void kernel_launch(void* const* d_in, const int* in_sizes, int n_in,
                              void* d_out, int out_size, void* d_ws, size_t ws_size,
                              hipStream_t stream) {
  const float* x    = (const float*)d_in[0];
  const float* pos  = (const float*)d_in[1];
  const float* mask = (const float*)d_in[2];
  const float* eattr= (const float*)d_in[3];
  const int*   ei   = (const int*)d_in[4];
  const float* We1  = (const float*)d_in[5];
  const float* be1  = (const float*)d_in[6];
  const float* We2  = (const float*)d_in[7];
  const float* be2  = (const float*)d_in[8];
  const float* Watt = (const float*)d_in[9];
  const float* batt = (const float*)d_in[10];
  const float* Wn1  = (const float*)d_in[11];
  const float* bn1  = (const float*)d_in[12];
  const float* Wn2  = (const float*)d_in[13];
  const float* bn2  = (const float*)d_in[14];
  const float* cW1  = (const float*)d_in[15];
  const float* cb1  = (const float*)d_in[16];
  const float* cW2  = (const float*)d_in[17];
  const float* cb2  = (const float*)d_in[18];
  const float* cW3  = (const float*)d_in[19];

  char* p = (char*)d_ws;
  auto carve = [&](size_t bytes) { char* r = p; p += (bytes + 511) & ~(size_t)511; return r; };
  short*   H1RC  = (short*)carve((size_t)NN * 256 * 2);
  uint8_t* eaF8  = (uint8_t*)carve((size_t)NE * 16 + 256);
  int*     rowS  = (int*)carve((size_t)NE * 4);
  int*     colS  = (int*)carve((size_t)NE * 4);
  float*   ndS   = (float*)carve((size_t)NE * 3 * 4);
  float*   agg   = (float*)carve((size_t)NN * 128 * 4);
  float*   xcur  = (float*)carve((size_t)NN * 128 * 4);
  float*   pagg  = (float*)carve((size_t)NN * 3 * 4);
  uint8_t* W1f8  = (uint8_t*)carve(3 * 36864);
  short*   W2sw  = (short*)carve(3 * 16384 * 2);
  short*   Wn1sw = (short*)carve(2 * 32768 * 2);
  short*   Wn2sw = (short*)carve(2 * 16384 * 2);
  short*   W1csw = (short*)carve(3 * 32768 * 2);
  int*     cnt   = (int*)carve((size_t)NN * 4);
  int*     offs  = (int*)carve((size_t)NN * 4);
  int*     bsum  = (int*)carve(256 * 4);
  int*     sortedIdx = (int*)carve((size_t)NE * 4);

  float* xout_f = (float*)d_out;        // N*128
  float* pout_f = xout_f + NN * 128;    // N*3

  // fused: weight prep + histogram
  hipMemsetAsync(cnt, 0, (size_t)NN * 4, stream);
  k_setup1<<<1392 + 3125, 256, 0, stream>>>(We1, We2, Wn1, Wn2, cW1, cW2,
                                            W1f8, W2sw, Wn1sw, Wn2sw, W1csw, ei, cnt);
  k_scan_block<<<196, 256, 0, stream>>>(cnt, offs, bsum);
  k_scan_top<<<1, 256, 0, stream>>>(bsum);
  // fused: layer-0 H1 (+agg zero) + scatter (scan_add folded in)
  k_setup2<<<782 + 3125, 256, 0, stream>>>(x, W1csw, be1, H1RC, agg,
                                           ei, offs, bsum, sortedIdx);
  k_edge_pre<<<3125, 256, 0, stream>>>(pos, eattr, ei, sortedIdx,
                                       rowS, colS, eaF8, ndS, pagg);

  // layer 0
  k_edge_gemm<0><<<12500, 256, 0, stream>>>(H1RC, eaF8, rowS, colS,
      W1f8, W2sw, be2, Watt, batt, (const float*)nullptr, agg);
  k_node_gemm<<<782, 256, 0, stream>>>(agg, Wn1sw, Wn2sw, bn1, bn2,
      x, xcur, W1csw + 32768, be1 + 128, H1RC, agg);   // zeroes agg for layer 1

  // layer 1
  k_edge_gemm<0><<<12500, 256, 0, stream>>>(H1RC, eaF8, rowS, colS,
      W1f8 + 36864, W2sw + 16384, be2 + 128, Watt + 128, batt + 1,
      (const float*)nullptr, agg);
  k_node_gemm<<<782, 256, 0, stream>>>(agg, Wn1sw + 32768, Wn2sw + 16384,
      bn1 + 128, bn2 + 128, xcur, xout_f, W1csw + 2 * 32768, cb1, H1RC,
      (float*)nullptr);

  // coord stage
  k_edge_gemm<1><<<12500, 256, 0, stream>>>(H1RC, eaF8, rowS, colS,
      W1f8 + 2 * 36864, W2sw + 2 * 16384, cb2, cW3, (const float*)nullptr, ndS, pagg);
  k_pos_final<<<587, 256, 0, stream>>>(pos, mask, pagg, pout_f);
}

// Round 9
// 707.140 us; speedup vs baseline: 1.0078x; 1.0078x over previous
//
#include <hip/hip_runtime.h>
#include <hip/hip_bf16.h>
#include <stdint.h>

#define NN 50000
#define NE 800000
#define HH 128

typedef __bf16 bf16x8 __attribute__((ext_vector_type(8)));
typedef float  f32x4  __attribute__((ext_vector_type(4)));
typedef long   f8frag;   // 8 fp8 bytes = i64 MFMA operand

__device__ __forceinline__ unsigned short f2bf(float f) {
  union { float f; uint32_t u; } v; v.f = f;
  uint32_t r = v.u + 0x7FFFu + ((v.u >> 16) & 1u);
  return (unsigned short)(r >> 16);
}
__device__ __forceinline__ float b2f(unsigned short u) {
  union { float f; uint32_t u; } v; v.u = (uint32_t)u << 16; return v.f;
}
#if __has_builtin(__builtin_amdgcn_cvt_pk_bf16_f32)
typedef __bf16 bf16x2 __attribute__((ext_vector_type(2)));
__device__ __forceinline__ uint32_t pack2bf(float a, float b) {
  union { bf16x2 v; uint32_t u; } t;
  t.v = __builtin_amdgcn_cvt_pk_bf16_f32(a, b);
  return t.u;
}
#else
__device__ __forceinline__ uint32_t pack2bf(float a, float b) {
  return (uint32_t)f2bf(a) | ((uint32_t)f2bf(b) << 16);
}
#endif
__device__ __forceinline__ uint8_t f2fp8(float v) {
  return (uint8_t)(__builtin_amdgcn_cvt_pk_fp8_f32(v, 0.f, 0, false) & 0xff);
}
// fast silu/sigmoid
__device__ __forceinline__ float silu_f(float x) {
  return x * __builtin_amdgcn_rcpf(1.f + __expf(-x));
}
__device__ __forceinline__ float sigm_f(float x) {
  return __builtin_amdgcn_rcpf(1.f + __expf(-x));
}

// LDS tile blocks (bf16): [rows][32 k], 16B chunk c stored at c ^ ((row>>1)&3)
__device__ __forceinline__ bf16x8 frag_ld(const short* blk, int row, int q) {
  int c = q ^ ((row >> 1) & 3);
  return *(const bf16x8*)(blk + row * 32 + c * 8);
}
// bf16 global weight frag offset (swizzled prep layout, short-indexed)
__device__ __forceinline__ int wfrag_off(int row, int q) {
  return row * 32 + ((q ^ ((row >> 1) & 3)) * 8);
}
// build bf16x8 frag from 8 consecutive f32 (16B-aligned), with scale folded
__device__ __forceinline__ bf16x8 fragf32(const float* src, float sc) {
  float4 lo = *(const float4*)src;
  float4 hi = *(const float4*)(src + 4);
  union { uint32_t u[4]; bf16x8 v; } t;
  t.u[0] = pack2bf(lo.x * sc, lo.y * sc);
  t.u[1] = pack2bf(lo.z * sc, lo.w * sc);
  t.u[2] = pack2bf(hi.x * sc, hi.y * sc);
  t.u[3] = pack2bf(hi.z * sc, hi.w * sc);
  return t.v;
}

// ---------------- weight prep body ----------------
__device__ void prep_weights_body(int idx, const float* We1, const float* We2,
                                  const float* Wn1, const float* Wn2,
                                  const float* cW1, const float* cW2,
                                  uint8_t* W1f8, short* W2sw, short* Wn1sw,
                                  short* Wn2sw, short* W1csw) {
  if (idx < 110592) {                      // fp8 W1 (ks=265)
    int l = idx / 36864, rem = idx % 36864;
    const float* s = (l == 0) ? We1 : (l == 1) ? We1 + 33920 : cW1;
    int kkb = rem >> 12, r2 = rem & 4095;
    int n = r2 >> 5, kw = r2 & 31;
    int k = kkb * 32 + kw;
    float v = (k < 265) ? s[k * 128 + n] : 0.f;
    W1f8[idx] = f2fp8(v);
    return;
  }
  idx -= 110592;
  if (idx < 49152) {                       // bf16 W2, 3 sets, ks=128
    int l = idx >> 14, rem = idx & 16383;
    const float* s = (l == 0) ? We2 : (l == 1) ? We2 + 16384 : cW2;
    int kkb = rem >> 12, r2 = rem & 4095, n = r2 >> 5, kw = r2 & 31;
    int cp = kw >> 3, j = kw & 7, c = cp ^ ((n >> 1) & 3);
    int k = kkb * 32 + c * 8 + j;
    W2sw[(l << 14) + (rem)] = (short)f2bf(s[k * 128 + n]);
    return;
  }
  idx -= 49152;
  if (idx < 65536) {                       // bf16 Wn1, 2 sets, ks=256
    int l = idx >> 15, rem = idx & 32767;
    const float* s = Wn1 + l * 32768;
    int kkb = rem >> 12, r2 = rem & 4095, n = r2 >> 5, kw = r2 & 31;
    int cp = kw >> 3, j = kw & 7, c = cp ^ ((n >> 1) & 3);
    int k = kkb * 32 + c * 8 + j;
    Wn1sw[(l << 15) + rem] = (short)f2bf(s[k * 128 + n]);
    return;
  }
  idx -= 65536;
  if (idx < 32768) {                       // bf16 Wn2, 2 sets, ks=128
    int l = idx >> 14, rem = idx & 16383;
    const float* s = Wn2 + l * 16384;
    int kkb = rem >> 12, r2 = rem & 4095, n = r2 >> 5, kw = r2 & 31;
    int cp = kw >> 3, j = kw & 7, c = cp ^ ((n >> 1) & 3);
    int k = kkb * 32 + c * 8 + j;
    Wn2sw[(l << 14) + rem] = (short)f2bf(s[k * 128 + n]);
    return;
  }
  idx -= 32768;
  if (idx < 98304) {                       // bf16 W1cat, 3 sets, [4kk][256n][32k]
    int l = idx / 32768, rem = idx % 32768;
    const float* s = (l == 0) ? We1 : (l == 1) ? We1 + 33920 : cW1;
    int kkb = rem >> 13, r2 = rem & 8191, n = r2 >> 5, kw = r2 & 31;
    int cp = kw >> 3, j = kw & 7, c = cp ^ ((n >> 1) & 3);
    int k = kkb * 32 + c * 8 + j;          // 0..127
    float v = (n < 128) ? s[k * 128 + n] : s[(128 + k) * 128 + (n - 128)];
    W1csw[l * 32768 + rem] = (short)f2bf(v);
  }
}

// fused: weight prep (blocks 0..1391) + edge histogram (blocks 1392..)
__global__ void k_setup1(const float* We1, const float* We2, const float* Wn1,
                         const float* Wn2, const float* cW1, const float* cW2,
                         uint8_t* W1f8, short* W2sw, short* Wn1sw, short* Wn2sw,
                         short* W1csw, const int* __restrict__ ei,
                         int* __restrict__ cnt) {
  if (blockIdx.x < 1392) {
    prep_weights_body(blockIdx.x * 256 + threadIdx.x, We1, We2, Wn1, Wn2, cW1, cW2,
                      W1f8, W2sw, Wn1sw, Wn2sw, W1csw);
  } else {
    int e = (blockIdx.x - 1392) * 256 + threadIdx.x;
    if (e < NE) atomicAdd(&cnt[ei[e]], 1);
  }
}

// ---------------- small prep / epilogue kernels ----------------
// forward-perm: per sorted slot p, gather original edge e = sortedIdx[p];
// all writes coalesced. Also zeroes pagg (folds a memset dispatch).
__global__ void k_edge_pre(const float* __restrict__ pos, const float* __restrict__ eattr,
                           const int* __restrict__ ei, const int* __restrict__ sortedIdx,
                           int* __restrict__ rowS, int* __restrict__ colS,
                           uint8_t* __restrict__ eaF8, float* __restrict__ ndS,
                           float* __restrict__ pagg) {
  int p = blockIdx.x * 256 + threadIdx.x;
  if (p < NN * 3) pagg[p] = 0.f;
  if (p >= NE) return;
  int e = sortedIdx[p];
  int r = ei[e], c = ei[NE + e];
  float dx = pos[r * 3 + 0] - pos[c * 3 + 0];
  float dy = pos[r * 3 + 1] - pos[c * 3 + 1];
  float dz = pos[r * 3 + 2] - pos[c * 3 + 2];
  float d2 = dx * dx + dy * dy + dz * dz;
  float invd = __builtin_amdgcn_rcpf(sqrtf(d2) + 1.f);   // NC = 1.0
  rowS[p] = r;
  colS[p] = c;
  ndS[p * 3 + 0] = dx * invd;
  ndS[p * 3 + 1] = dy * invd;
  ndS[p * 3 + 2] = dz * invd;
  const float* ea = eattr + (size_t)e * 8;
  uint32_t w0 = __builtin_amdgcn_cvt_pk_fp8_f32(d2, ea[0], 0, false);
  w0 = __builtin_amdgcn_cvt_pk_fp8_f32(ea[1], ea[2], w0, true);
  uint32_t w1 = __builtin_amdgcn_cvt_pk_fp8_f32(ea[3], ea[4], 0, false);
  w1 = __builtin_amdgcn_cvt_pk_fp8_f32(ea[5], ea[6], w1, true);
  uint32_t w2 = __builtin_amdgcn_cvt_pk_fp8_f32(ea[7], 0.f, 0, false);
  uint4 v = {w0, w1, w2, 0u};
  *(uint4*)(eaF8 + (size_t)p * 16) = v;
}
__global__ void k_pos_final(const float* __restrict__ pos, const float* __restrict__ mask,
                            const float* __restrict__ pagg, float* __restrict__ out) {
  int i = blockIdx.x * 256 + threadIdx.x;
  if (i < NN * 3) out[i] = pos[i] + pagg[i] * 0.01f * mask[i / 3];
}

// ---------------- CSR sort: fused scan (block scan + last-block top scan) ------------
__global__ void k_scan_block(const int* __restrict__ cnt, int* __restrict__ offs,
                             int* __restrict__ bsum, int* __restrict__ done) {
  __shared__ int s[256];
  __shared__ int elected;
  int i = blockIdx.x * 256 + threadIdx.x;
  int v = (i < NN) ? cnt[i] : 0;
  s[threadIdx.x] = v;
  __syncthreads();
#pragma unroll
  for (int d = 1; d < 256; d <<= 1) {
    int t = (threadIdx.x >= d) ? s[threadIdx.x - d] : 0;
    __syncthreads();
    s[threadIdx.x] += t;
    __syncthreads();
  }
  if (i < NN) offs[i] = s[threadIdx.x] - v;
  if (threadIdx.x == 255) bsum[blockIdx.x] = s[255];
  __syncthreads();
  // last-arriving block performs the 196-wide top-level exclusive scan of bsum
  if (threadIdx.x == 0) {
    __threadfence();
    elected = (atomicAdd(done, 1) == (int)gridDim.x - 1) ? 1 : 0;
  }
  __syncthreads();
  if (!elected) return;
  // device-scope atomic reads: bypass potentially-stale local L2 lines
  int v2 = (threadIdx.x < 196) ? atomicOr(&bsum[threadIdx.x], 0) : 0;
  s[threadIdx.x] = v2;
  __syncthreads();
#pragma unroll
  for (int d = 1; d < 256; d <<= 1) {
    int t = (threadIdx.x >= d) ? s[threadIdx.x - d] : 0;
    __syncthreads();
    s[threadIdx.x] += t;
    __syncthreads();
  }
  if (threadIdx.x < 196) bsum[threadIdx.x] = s[threadIdx.x] - v2;
}

// ---------------- per-node H1 body (layer 0, reads x f32; zeroes agg) ----------------
__device__ void h1_body(int tile, int tid, const float* __restrict__ x,
                        const short* __restrict__ W1c, const float* __restrict__ b1,
                        short* __restrict__ H1RC, float* __restrict__ aggZ) {
  const int lane = tid & 63, w = tid >> 6;
  const int ln = lane & 15, q = lane >> 4;
  {
    float4* a4 = (float4*)aggZ;
    const float4 z4 = {0.f, 0.f, 0.f, 0.f};
#pragma unroll
    for (int k = 0; k < 8; ++k) {
      int i4 = tile * 2048 + k * 256 + tid;
      if (i4 < NN * 32) a4[i4] = z4;
    }
  }
  size_t nbase[4];
  int wofs[4];
#pragma unroll
  for (int i = 0; i < 4; ++i) {
    int node = tile * 64 + i * 16 + ln;
    nbase[i] = (size_t)(node < NN ? node : (NN - 1)) * 128;
    int row = w * 64 + i * 16 + ln;
    wofs[i] = row * 32 + ((q ^ ((row >> 1) & 3)) * 8);
  }
  f32x4 acc[4][4];
  const f32x4 zero4 = {0.f, 0.f, 0.f, 0.f};
#pragma unroll
  for (int mi = 0; mi < 4; ++mi)
#pragma unroll
    for (int ni = 0; ni < 4; ++ni) acc[mi][ni] = zero4;
#pragma unroll
  for (int kk = 0; kk < 4; ++kk) {
    bf16x8 af[4], bfr[4];
#pragma unroll
    for (int i = 0; i < 4; ++i) af[i] = fragf32(x + nbase[i] + kk * 32 + q * 8, 1.f);
#pragma unroll
    for (int i = 0; i < 4; ++i) bfr[i] = *(const bf16x8*)(W1c + kk * 8192 + wofs[i]);
#pragma unroll
    for (int mi = 0; mi < 4; ++mi)
#pragma unroll
      for (int ni = 0; ni < 4; ++ni)
        acc[mi][ni] = __builtin_amdgcn_mfma_f32_16x16x32_bf16(af[mi], bfr[ni], acc[mi][ni], 0, 0, 0);
  }
  float b1v[4];
#pragma unroll
  for (int ni = 0; ni < 4; ++ni) {
    int ch = w * 64 + ni * 16 + ln;
    b1v[ni] = (ch < 128) ? b1[ch] : 0.f;
  }
#pragma unroll
  for (int mi = 0; mi < 4; ++mi)
#pragma unroll
    for (int r = 0; r < 4; ++r) {
      int node = tile * 64 + mi * 16 + q * 4 + r;
      if (node < NN) {
        ushort4 pk;
        pk.x = f2bf(acc[mi][0][r] + b1v[0]);
        pk.y = f2bf(acc[mi][1][r] + b1v[1]);
        pk.z = f2bf(acc[mi][2][r] + b1v[2]);
        pk.w = f2bf(acc[mi][3][r] + b1v[3]);
        *(ushort4*)(H1RC + (size_t)node * 256 + w * 64 + ln * 4) = pk;
      }
    }
}

// fused: layer-0 H1 (blocks 0..781) + sort scatter (blocks 782..)
// scatter folds the scan_add: slot = local prefix atomic + block base
__global__ __launch_bounds__(256) void k_setup2(
    const float* __restrict__ x, const short* __restrict__ W1c,
    const float* __restrict__ b1, short* __restrict__ H1RC, float* __restrict__ aggZ,
    const int* __restrict__ ei, int* __restrict__ offs, const int* __restrict__ bsum,
    int* __restrict__ sortedIdx) {
  if (blockIdx.x < 782) {
    h1_body(blockIdx.x, threadIdx.x, x, W1c, b1, H1RC, aggZ);
  } else {
    int e = (blockIdx.x - 782) * 256 + threadIdx.x;
    if (e < NE) {
      int r = ei[e];
      sortedIdx[atomicAdd(&offs[r], 1) + bsum[r >> 8]] = e;
    }
  }
}

// ---------------- fused edge/coord MLP (edges presorted by row) ----------------
// h1 = silu(H1RC[row].lo + H1RC[col].hi + ea@W1ea). Attention rides in the
// segment-sum S matrix. XCD-bijective tile swizzle. Single reused accumulator.
// GEMM2 kk=0 weight frags hoisted ABOVE the epilogue-1 barrier (compiler cannot
// hoist loads across __syncthreads) to hide the barrier drain.
template <int COORD>
__global__ __launch_bounds__(256, 5) void k_edge_gemm(
    const short* __restrict__ H1RC, const uint8_t* __restrict__ eaF8,
    const int* __restrict__ rowS, const int* __restrict__ colS,
    const uint8_t* __restrict__ W1f8, const short* __restrict__ W2l,
    const float* __restrict__ b2,
    const float* __restrict__ wred, const float* __restrict__ batt,
    const float* __restrict__ ndS, float* outAcc) {
  __shared__ __align__(16) short A2s[8192];  // h1^T 4x[64e][32c]; then M 2x[128c][32e]
  __shared__ float redp[64][2];
  __shared__ __align__(16) unsigned short attb[64];
  __shared__ int srow[64];
  __shared__ __align__(8) unsigned char srunS[64];
  __shared__ int runrowS[64];
  __shared__ int cntS[1];

  const int tid = threadIdx.x;
  const int lane = tid & 63;
  const int w = tid >> 6;
  const int ln = lane & 15, q = lane >> 4;
  const int wm = w >> 1, wn = w & 1;

  // XCD-bijective swizzle (8 XCDs)
  const int nwg = gridDim.x;
  const int qq = nwg >> 3, rr = nwg & 7;
  const int xcd = blockIdx.x & 7, bidx = blockIdx.x >> 3;
  const int tile = (xcd < rr ? xcd * (qq + 1) : rr * (qq + 1) + (xcd - rr) * qq) + bidx;
  const int ebase = tile * 64;

  // ---- wave0: segmented-run scan over sorted rows (published by epilogue1 barrier)
  bool is_start = false;
  if (w == 0) {
    int myrow = rowS[ebase + tid];
    srow[tid] = myrow;
    int prevrow = (tid > 0) ? rowS[ebase + tid - 1] : (myrow ^ 1);
    is_start = (tid == 0) || (myrow != prevrow);
    unsigned long long bmask = __ballot(is_start);
    if (tid == 0) cntS[0] = __popcll(bmask);
    int run = __popcll(bmask & ((1ull << lane) - 1ull)) + (is_start ? 1 : 0) - 1;
    srunS[tid] = (unsigned char)run;
    if (is_start) runrowS[run] = myrow;
  }

  // per-lane sources (uint32 offsets -> saddr-form loads)
  const int e0 = wm * 32 + ln, e1 = e0 + 16;
  const uint32_t cbp = (uint32_t)(wn * 64 + q * 16);
  const uint32_t hr0 = (uint32_t)rowS[ebase + e0] * 256u + cbp;
  const uint32_t hr1 = (uint32_t)rowS[ebase + e1] * 256u + cbp;
  const uint32_t hc0 = (uint32_t)colS[ebase + e0] * 256u + 128u + cbp;
  const uint32_t hc1 = (uint32_t)colS[ebase + e1] * 256u + 128u + cbp;
  const uint32_t ea0 = (uint32_t)(ebase + e0) * 16u + (uint32_t)((q & 1) * 8);
  const uint32_t ea1 = (uint32_t)(ebase + e1) * 16u + (uint32_t)((q & 1) * 8);
  int wofs8[4], wofs[4];
#pragma unroll
  for (int i = 0; i < 4; ++i) {
    wofs8[i] = (wn * 64 + i * 16 + ln) * 32 + q * 8;
    wofs[i] = wfrag_off(wn * 64 + i * 16 + ln, q);
  }

  // H1 gathers: 16B each
  union U8 { uint4 v; unsigned short s[8]; };
  U8 xr[2][2], xc[2][2];
  xr[0][0].v = *(const uint4*)(H1RC + hr0);
  xr[0][1].v = *(const uint4*)(H1RC + hr0 + 8);
  xr[1][0].v = *(const uint4*)(H1RC + hr1);
  xr[1][1].v = *(const uint4*)(H1RC + hr1 + 8);
  xc[0][0].v = *(const uint4*)(H1RC + hc0);
  xc[0][1].v = *(const uint4*)(H1RC + hc0 + 8);
  xc[1][0].v = *(const uint4*)(H1RC + hc1);
  xc[1][1].v = *(const uint4*)(H1RC + hc1 + 8);

  f32x4 acc[4][2];                           // reused: GEMM1 then GEMM2
  const f32x4 zero4 = {0.f, 0.f, 0.f, 0.f};
#pragma unroll
  for (int ni = 0; ni < 4; ++ni)
#pragma unroll
    for (int mi = 0; mi < 2; ++mi) acc[ni][mi] = zero4;

  // -------- ea-only fp8 MFMA step --------
  {
    const uint8_t* W1ea = W1f8 + 8 * 4096;
    f8frag wf[4], hf[2];
#pragma unroll
    for (int i = 0; i < 4; ++i) wf[i] = *(const f8frag*)(W1ea + wofs8[i]);
    hf[0] = (q < 2) ? *(const f8frag*)(eaF8 + ea0) : 0L;
    hf[1] = (q < 2) ? *(const f8frag*)(eaF8 + ea1) : 0L;
#pragma unroll
    for (int ni = 0; ni < 4; ++ni)
#pragma unroll
      for (int mi = 0; mi < 2; ++mi)
        acc[ni][mi] = __builtin_amdgcn_mfma_f32_16x16x32_fp8_fp8(wf[ni], hf[mi], acc[ni][mi], 0, 0, 0);
  }

  // hoist GEMM2 kk=0 weight frags above the barrier (in flight during drain)
  bf16x8 wf0[4];
#pragma unroll
  for (int i = 0; i < 4; ++i) wf0[i] = *(const bf16x8*)(W2l + wofs[i]);

  // -------- epilogue1: silu(ea + H1R[row] + H1C[col]) -> A2s bf16 [edge][chan] --------
#pragma unroll
  for (int ni = 0; ni < 4; ++ni) {
    int cb = wn * 64 + ni * 16 + q * 4;
    int kkb = cb >> 5, cc = (cb >> 3) & 3, j0 = cb & 7;
#pragma unroll
    for (int mi = 0; mi < 2; ++mi) {
      int edge = wm * 32 + mi * 16 + ln;
      int addr = kkb * 2048 + edge * 32 + ((cc ^ ((edge >> 1) & 3)) * 8) + j0;
      float h0 = silu_f(acc[ni][mi][0] + b2f(xr[mi][0].s[ni]) + b2f(xc[mi][0].s[ni]));
      float h1 = silu_f(acc[ni][mi][1] + b2f(xr[mi][0].s[4 + ni]) + b2f(xc[mi][0].s[4 + ni]));
      float h2 = silu_f(acc[ni][mi][2] + b2f(xr[mi][1].s[ni]) + b2f(xc[mi][1].s[ni]));
      float h3 = silu_f(acc[ni][mi][3] + b2f(xr[mi][1].s[4 + ni]) + b2f(xc[mi][1].s[4 + ni]));
      uint2 pk;
      pk.x = pack2bf(h0, h1);
      pk.y = pack2bf(h2, h3);
      *(uint2*)(A2s + addr) = pk;
    }
  }
  __syncthreads();

  // epilogue2 constants loaded before the MFMA loop (hide under GEMM2)
  float4 b2v[4], wv[4];
#pragma unroll
  for (int ni = 0; ni < 4; ++ni) {
    b2v[ni] = *(const float4*)(b2 + wn * 64 + ni * 16 + q * 4);
    wv[ni]  = *(const float4*)(wred + wn * 64 + ni * 16 + q * 4);
  }

  // -------- GEMM2 (bf16) into the SAME acc registers --------
#pragma unroll
  for (int ni = 0; ni < 4; ++ni)
#pragma unroll
    for (int mi = 0; mi < 2; ++mi) acc[ni][mi] = zero4;
#pragma unroll
  for (int kk = 0; kk < 4; ++kk) {
    bf16x8 wf[4], hf[2];
#pragma unroll
    for (int i = 0; i < 4; ++i)
      wf[i] = (kk == 0) ? wf0[i] : *(const bf16x8*)(W2l + kk * 4096 + wofs[i]);
#pragma unroll
    for (int i = 0; i < 2; ++i) hf[i] = frag_ld(A2s + kk * 2048, wm * 32 + i * 16 + ln, q);
#pragma unroll
    for (int ni = 0; ni < 4; ++ni)
#pragma unroll
      for (int mi = 0; mi < 2; ++mi)
        acc[ni][mi] = __builtin_amdgcn_mfma_f32_16x16x32_bf16(wf[ni], hf[mi], acc[ni][mi], 0, 0, 0);
  }

  // -------- epilogue2: silu + attention/phi dot --------
  float p[2] = {0.f, 0.f};
#pragma unroll
  for (int ni = 0; ni < 4; ++ni)
#pragma unroll
    for (int mi = 0; mi < 2; ++mi)
#pragma unroll
      for (int r = 0; r < 4; ++r) {
        float v = silu_f(acc[ni][mi][r] + ((const float*)&b2v[ni])[r]);
        acc[ni][mi][r] = v;
        p[mi] += v * ((const float*)&wv[ni])[r];
      }
#pragma unroll
  for (int mi = 0; mi < 2; ++mi) {
    p[mi] += __shfl_xor(p[mi], 16, 64);
    p[mi] += __shfl_xor(p[mi], 32, 64);
  }
  if (lane < 16) {
#pragma unroll
    for (int mi = 0; mi < 2; ++mi) redp[wm * 32 + mi * 16 + ln][wn] = p[mi];
  }
  __syncthreads();   // redp ready; all waves done with A2s

  if (COORD == 0) {
    if (tid < 64) attb[tid] = f2bf(sigm_f(redp[tid][0] + redp[tid][1] + batt[0]));
#pragma unroll
    for (int ni = 0; ni < 4; ++ni)
#pragma unroll
      for (int mi = 0; mi < 2; ++mi) {
        int eb = mi * 16 + ln;
        int cE = (eb >> 3) & 3, jE = eb & 7;
#pragma unroll
        for (int r = 0; r < 4; ++r) {
          int chan2 = wn * 64 + ni * 16 + q * 4 + r;
          int addr = wm * 4096 + chan2 * 32 + ((cE ^ ((chan2 >> 1) & 3)) * 8) + jE;
          union { float f; uint32_t u; } vv;
          vv.f = acc[ni][mi][r];
          A2s[addr] = (short)((vv.u + 0x8000u) >> 16);
        }
      }
    __syncthreads();   // attb + M ready
    // segment-sum via MFMA: agg[run][chan] = S[run][edge] @ M[edge][chan]
    const int nruns = cntS[0];
    bf16x8 bfrg[2][2];
#pragma unroll
    for (int kk = 0; kk < 2; ++kk)
#pragma unroll
      for (int ni = 0; ni < 2; ++ni)
        bfrg[kk][ni] = frag_ld(A2s + kk * 4096, w * 32 + ni * 16 + ln, q);
    const int npass = (nruns + 15) >> 4;
    for (int pp = 0; pp < npass; ++pp) {
      const unsigned int base = pp * 16;
      f32x4 a3c[2] = {zero4, zero4};
#pragma unroll
      for (int kk = 0; kk < 2; ++kk) {
        uint2 sb = *(const uint2*)(srunS + kk * 32 + q * 8);
        U8 ab;
        ab.v = *(const uint4*)(attb + kk * 32 + q * 8);
        union { short s[8]; bf16x8 v; } af;
#pragma unroll
        for (int j = 0; j < 4; ++j)
          af.s[j] = (((sb.x >> (8 * j)) & 255u) == base + (unsigned)ln) ? (short)ab.s[j] : (short)0;
#pragma unroll
        for (int j = 0; j < 4; ++j)
          af.s[4 + j] = (((sb.y >> (8 * j)) & 255u) == base + (unsigned)ln) ? (short)ab.s[4 + j] : (short)0;
        a3c[0] = __builtin_amdgcn_mfma_f32_16x16x32_bf16(af.v, bfrg[kk][0], a3c[0], 0, 0, 0);
        a3c[1] = __builtin_amdgcn_mfma_f32_16x16x32_bf16(af.v, bfrg[kk][1], a3c[1], 0, 0, 0);
      }
#pragma unroll
      for (int ni = 0; ni < 2; ++ni)
#pragma unroll
        for (int r = 0; r < 4; ++r) {
          int run = (int)base + q * 4 + r;
          if (run < nruns) {
            int rw = runrowS[run];
            float* dst = &outAcc[(size_t)rw * 128 + (w * 32 + ni * 16 + ln)];
            // interior run: row wholly inside this tile -> exclusive, plain store
            if (run > 0 && run < nruns - 1) *dst = a3c[ni][r];
            else atomicAdd(dst, a3c[ni][r]);
          }
        }
    }
  } else {
    float* ndl = (float*)A2s;   // reuse: [64][3]
    if (tid < 64) {
      float phi = redp[tid][0] + redp[tid][1];
      ndl[tid * 3 + 0] = ndS[(size_t)(ebase + tid) * 3 + 0] * phi;
      ndl[tid * 3 + 1] = ndS[(size_t)(ebase + tid) * 3 + 1] * phi;
      ndl[tid * 3 + 2] = ndS[(size_t)(ebase + tid) * 3 + 2] * phi;
    }
    __syncthreads();
    if (is_start) {   // run-start walkers (wave0 only)
      int myrow = srow[tid];
      float s0 = 0.f, s1 = 0.f, s2 = 0.f;
      int j = tid;
      for (; j < 64 && srow[j] == myrow; ++j) {
        s0 += ndl[j * 3 + 0];
        s1 += ndl[j * 3 + 1];
        s2 += ndl[j * 3 + 2];
      }
      bool excl = (tid > 0) && (j < 64);   // run starts and ends inside tile
      if (excl) {
        outAcc[myrow * 3 + 0] = s0;
        outAcc[myrow * 3 + 1] = s1;
        outAcc[myrow * 3 + 2] = s2;
      } else {
        atomicAdd(&outAcc[myrow * 3 + 0], s0);
        atomicAdd(&outAcc[myrow * 3 + 1], s1);
        atomicAdd(&outAcc[myrow * 3 + 2], s2);
      }
    }
  }
}

// ---------------- node MLP GEMM + fused next-layer H1 (64-node tiles, bf16) ----------
__global__ __launch_bounds__(256) void k_node_gemm(
    const float* __restrict__ agg,
    const short* __restrict__ Wn1l, const short* __restrict__ Wn2l,
    const float* __restrict__ b1, const float* __restrict__ b2,
    const float* __restrict__ xres, float* __restrict__ xout,
    const short* __restrict__ W1cN, const float* __restrict__ b1N,
    short* __restrict__ H1RC, float* __restrict__ aggZ) {
  __shared__ short A2s[4 * 2048];

  const int tid = threadIdx.x;
  const int lane = tid & 63;
  const int w = tid >> 6;
  const int ln = lane & 15, q = lane >> 4;
  const int wm = w >> 1, wn = w & 1;
  const int tile = blockIdx.x;

  size_t nbase[2];
  int wofs[4];
#pragma unroll
  for (int i = 0; i < 2; ++i) {
    int node = tile * 64 + wm * 32 + i * 16 + ln;
    nbase[i] = (size_t)(node < NN ? node : (NN - 1)) * 128;
  }
#pragma unroll
  for (int i = 0; i < 4; ++i) wofs[i] = wfrag_off(wn * 64 + i * 16 + ln, q);

  f32x4 acc[2][4];
  const f32x4 zero4 = {0.f, 0.f, 0.f, 0.f};
#pragma unroll
  for (int mi = 0; mi < 2; ++mi)
#pragma unroll
    for (int ni = 0; ni < 4; ++ni) acc[mi][ni] = zero4;

#pragma unroll
  for (int kk = 0; kk < 8; ++kk) {
    bf16x8 af[2], bfr[4];
#pragma unroll
    for (int i = 0; i < 2; ++i) {
      if (kk < 4) af[i] = fragf32(xres + nbase[i] + kk * 32 + q * 8, 1.f);
      else        af[i] = fragf32(agg + nbase[i] + (kk - 4) * 32 + q * 8, 0.01f);
    }
#pragma unroll
    for (int i = 0; i < 4; ++i) bfr[i] = *(const bf16x8*)(Wn1l + kk * 4096 + wofs[i]);
#pragma unroll
    for (int mi = 0; mi < 2; ++mi)
#pragma unroll
      for (int ni = 0; ni < 4; ++ni)
        acc[mi][ni] = __builtin_amdgcn_mfma_f32_16x16x32_bf16(af[mi], bfr[ni], acc[mi][ni], 0, 0, 0);
  }

  if (aggZ) {
    float4* a4 = (float4*)aggZ;
    const float4 z4 = {0.f, 0.f, 0.f, 0.f};
#pragma unroll
    for (int k = 0; k < 8; ++k) {
      int i4 = tile * 2048 + k * 256 + tid;
      if (i4 < NN * 32) a4[i4] = z4;
    }
  }

  float b1v[4];
#pragma unroll
  for (int ni = 0; ni < 4; ++ni) b1v[ni] = b1[wn * 64 + ni * 16 + ln];
#pragma unroll
  for (int mi = 0; mi < 2; ++mi)
#pragma unroll
    for (int ni = 0; ni < 4; ++ni) {
      int chan = wn * 64 + ni * 16 + ln;
      int kkb = chan >> 5, c = (chan >> 3) & 3, jj = chan & 7;
#pragma unroll
      for (int r = 0; r < 4; ++r) {
        int m = wm * 32 + mi * 16 + q * 4 + r;
        float v = silu_f(acc[mi][ni][r] + b1v[ni]);
        A2s[kkb * 2048 + m * 32 + ((c ^ ((m >> 1) & 3)) * 8) + jj] = (short)f2bf(v);
      }
    }
  __syncthreads();

  f32x4 acc2[2][4];
#pragma unroll
  for (int mi = 0; mi < 2; ++mi)
#pragma unroll
    for (int ni = 0; ni < 4; ++ni) acc2[mi][ni] = zero4;
#pragma unroll
  for (int kk = 0; kk < 4; ++kk) {
    bf16x8 af[2], bfr[4];
#pragma unroll
    for (int i = 0; i < 2; ++i) af[i] = frag_ld(A2s + kk * 2048, wm * 32 + i * 16 + ln, q);
#pragma unroll
    for (int i = 0; i < 4; ++i) bfr[i] = *(const bf16x8*)(Wn2l + kk * 4096 + wofs[i]);
#pragma unroll
    for (int mi = 0; mi < 2; ++mi)
#pragma unroll
      for (int ni = 0; ni < 4; ++ni)
        acc2[mi][ni] = __builtin_amdgcn_mfma_f32_16x16x32_bf16(af[mi], bfr[ni], acc2[mi][ni], 0, 0, 0);
  }

  float b2v[4];
#pragma unroll
  for (int ni = 0; ni < 4; ++ni) b2v[ni] = b2[wn * 64 + ni * 16 + ln];
#pragma unroll
  for (int mi = 0; mi < 2; ++mi)
#pragma unroll
    for (int r = 0; r < 4; ++r) {
      int m = wm * 32 + mi * 16 + q * 4 + r;
      int node = tile * 64 + m;
      if (node < NN) {
#pragma unroll
        for (int ni = 0; ni < 4; ++ni) {
          int chan = wn * 64 + ni * 16 + ln;
          float v = acc2[mi][ni][r] + b2v[ni] + xres[(size_t)node * 128 + chan];
          acc2[mi][ni][r] = v;
          xout[(size_t)node * 128 + chan] = v;
        }
      }
    }

  // ---- fused H1 for the next stage ----
  __syncthreads();
#pragma unroll
  for (int mi = 0; mi < 2; ++mi)
#pragma unroll
    for (int ni = 0; ni < 4; ++ni) {
      int chan = wn * 64 + ni * 16 + ln;
      int kkb = chan >> 5, c = (chan >> 3) & 3, jj = chan & 7;
#pragma unroll
      for (int r = 0; r < 4; ++r) {
        int m = wm * 32 + mi * 16 + q * 4 + r;
        A2s[kkb * 2048 + m * 32 + ((c ^ ((m >> 1) & 3)) * 8) + jj] = (short)f2bf(acc2[mi][ni][r]);
      }
    }
  __syncthreads();

  int wofsH[4];
#pragma unroll
  for (int i = 0; i < 4; ++i) {
    int row = w * 64 + i * 16 + ln;
    wofsH[i] = row * 32 + ((q ^ ((row >> 1) & 3)) * 8);
  }
  f32x4 acc3[4][4];
#pragma unroll
  for (int mi = 0; mi < 4; ++mi)
#pragma unroll
    for (int ni = 0; ni < 4; ++ni) acc3[mi][ni] = zero4;
#pragma unroll
  for (int kk = 0; kk < 4; ++kk) {
    bf16x8 af[4], bfr[4];
#pragma unroll
    for (int i = 0; i < 4; ++i) af[i] = frag_ld(A2s + kk * 2048, i * 16 + ln, q);
#pragma unroll
    for (int i = 0; i < 4; ++i) bfr[i] = *(const bf16x8*)(W1cN + kk * 8192 + wofsH[i]);
#pragma unroll
    for (int mi = 0; mi < 4; ++mi)
#pragma unroll
      for (int ni = 0; ni < 4; ++ni)
        acc3[mi][ni] = __builtin_amdgcn_mfma_f32_16x16x32_bf16(af[mi], bfr[ni], acc3[mi][ni], 0, 0, 0);
  }
  float b1v2[4];
#pragma unroll
  for (int ni = 0; ni < 4; ++ni) {
    int ch = w * 64 + ni * 16 + ln;
    b1v2[ni] = (ch < 128) ? b1N[ch] : 0.f;
  }
#pragma unroll
  for (int mi = 0; mi < 4; ++mi)
#pragma unroll
    for (int r = 0; r < 4; ++r) {
      int node = tile * 64 + mi * 16 + q * 4 + r;
      if (node < NN) {
        ushort4 pk;
        pk.x = f2bf(acc3[mi][0][r] + b1v2[0]);
        pk.y = f2bf(acc3[mi][1][r] + b1v2[1]);
        pk.z = f2bf(acc3[mi][2][r] + b1v2[2]);
        pk.w = f2bf(acc3[mi][3][r] + b1v2[3]);
        *(ushort4*)(H1RC + (size_t)node * 256 + w * 64 + ln * 4) = pk;
      }
    }
}

extern "C" void kernel_launch(void* const* d_in, const int* in_sizes, int n_in,
                              void* d_out, int out_size, void* d_ws, size_t ws_size,
                              hipStream_t stream) {
  const float* x    = (const float*)d_in[0];
  const float* pos  = (const float*)d_in[1];
  const float* mask = (const float*)d_in[2];
  const float* eattr= (const float*)d_in[3];
  const int*   ei   = (const int*)d_in[4];
  const float* We1  = (const float*)d_in[5];
  const float* be1  = (const float*)d_in[6];
  const float* We2  = (const float*)d_in[7];
  const float* be2  = (const float*)d_in[8];
  const float* Watt = (const float*)d_in[9];
  const float* batt = (const float*)d_in[10];
  const float* Wn1  = (const float*)d_in[11];
  const float* bn1  = (const float*)d_in[12];
  const float* Wn2  = (const float*)d_in[13];
  const float* bn2  = (const float*)d_in[14];
  const float* cW1  = (const float*)d_in[15];
  const float* cb1  = (const float*)d_in[16];
  const float* cW2  = (const float*)d_in[17];
  const float* cb2  = (const float*)d_in[18];
  const float* cW3  = (const float*)d_in[19];

  char* p = (char*)d_ws;
  auto carve = [&](size_t bytes) { char* r = p; p += (bytes + 511) & ~(size_t)511; return r; };
  short*   H1RC  = (short*)carve((size_t)NN * 256 * 2);
  uint8_t* eaF8  = (uint8_t*)carve((size_t)NE * 16 + 256);
  int*     rowS  = (int*)carve((size_t)NE * 4);
  int*     colS  = (int*)carve((size_t)NE * 4);
  float*   ndS   = (float*)carve((size_t)NE * 3 * 4);
  float*   agg   = (float*)carve((size_t)NN * 128 * 4);
  float*   xcur  = (float*)carve((size_t)NN * 128 * 4);
  float*   pagg  = (float*)carve((size_t)NN * 3 * 4);
  uint8_t* W1f8  = (uint8_t*)carve(3 * 36864);
  short*   W2sw  = (short*)carve(3 * 16384 * 2);
  short*   Wn1sw = (short*)carve(2 * 32768 * 2);
  short*   Wn2sw = (short*)carve(2 * 16384 * 2);
  short*   W1csw = (short*)carve(3 * 32768 * 2);
  int*     cnt   = (int*)carve((size_t)NN * 4 + 4);   // +4: 'done' counter at cnt[NN]
  int*     offs  = (int*)carve((size_t)NN * 4);
  int*     bsum  = (int*)carve(256 * 4);
  int*     sortedIdx = (int*)carve((size_t)NE * 4);
  int*     done  = cnt + NN;

  float* xout_f = (float*)d_out;        // N*128
  float* pout_f = xout_f + NN * 128;    // N*3

  // fused: weight prep + histogram
  hipMemsetAsync(cnt, 0, (size_t)NN * 4 + 4, stream);
  k_setup1<<<1392 + 3125, 256, 0, stream>>>(We1, We2, Wn1, Wn2, cW1, cW2,
                                            W1f8, W2sw, Wn1sw, Wn2sw, W1csw, ei, cnt);
  // fused scan: block scan + last-block top scan (replaces scan_block + scan_top)
  k_scan_block<<<196, 256, 0, stream>>>(cnt, offs, bsum, done);
  // fused: layer-0 H1 (+agg zero) + scatter (scan_add folded in)
  k_setup2<<<782 + 3125, 256, 0, stream>>>(x, W1csw, be1, H1RC, agg,
                                           ei, offs, bsum, sortedIdx);
  k_edge_pre<<<3125, 256, 0, stream>>>(pos, eattr, ei, sortedIdx,
                                       rowS, colS, eaF8, ndS, pagg);

  // layer 0
  k_edge_gemm<0><<<12500, 256, 0, stream>>>(H1RC, eaF8, rowS, colS,
      W1f8, W2sw, be2, Watt, batt, (const float*)nullptr, agg);
  k_node_gemm<<<782, 256, 0, stream>>>(agg, Wn1sw, Wn2sw, bn1, bn2,
      x, xcur, W1csw + 32768, be1 + 128, H1RC, agg);   // zeroes agg for layer 1

  // layer 1
  k_edge_gemm<0><<<12500, 256, 0, stream>>>(H1RC, eaF8, rowS, colS,
      W1f8 + 36864, W2sw + 16384, be2 + 128, Watt + 128, batt + 1,
      (const float*)nullptr, agg);
  k_node_gemm<<<782, 256, 0, stream>>>(agg, Wn1sw + 32768, Wn2sw + 16384,
      bn1 + 128, bn2 + 128, xcur, xout_f, W1csw + 2 * 32768, cb1, H1RC,
      (float*)nullptr);

  // coord stage
  k_edge_gemm<1><<<12500, 256, 0, stream>>>(H1RC, eaF8, rowS, colS,
      W1f8 + 2 * 36864, W2sw + 2 * 16384, cb2, cW3, (const float*)nullptr, ndS, pagg);
  k_pos_final<<<587, 256, 0, stream>>>(pos, mask, pagg, pout_f);
}